// Round 4
// baseline (270.547 us; speedup 1.0000x reference)
//
#include <hip/hip_runtime.h>

typedef __attribute__((ext_vector_type(4))) float          f32x4;
typedef __attribute__((ext_vector_type(8))) short          bf16x8;
typedef __attribute__((ext_vector_type(4))) unsigned short u16x4;
typedef __attribute__((ext_vector_type(8))) unsigned short u16x8;

__device__ __forceinline__ unsigned short f2bf(float f) {
  union { float f; unsigned u; } v; v.f = f;
  unsigned r = v.u + 0x7fffu + ((v.u >> 16) & 1u);   // RNE
  return (unsigned short)(r >> 16);
}

#define S_  128
#define I_  256
#define D_  64
#define P_  32
#define DO_ 128

// ---------------------------------------------------------------------------
// K1: LayerNorm + projections. Grid 1024: (i 0..255) x (sq 0..3, 32 s each).
//   LtT[i*32+p][s] , RtT[j*32+q][s]  (8192 x 128 bf16)
// ---------------------------------------------------------------------------
__global__ __launch_bounds__(256) void ln_proj(
    const float* __restrict__ M,  const float* __restrict__ gamma,
    const float* __restrict__ beta,
    const float* __restrict__ Wa, const float* __restrict__ ba,
    const float* __restrict__ Wb, const float* __restrict__ bb,
    unsigned short* __restrict__ LtT, unsigned short* __restrict__ RtT)
{
  __shared__ __align__(16) float mnAll[32 * 68];   // [s_local][d]
  __shared__ __align__(16) float lsm[32 * 33];     // [s_local][p]
  __shared__ __align__(16) float rsm[32 * 33];

  const int tid  = threadIdx.x;
  const int lane = tid & 63;
  const int w    = tid >> 6;            // wave 0..3
  const int i    = blockIdx.x >> 2;     // residue 0..255
  const int sq   = blockIdx.x & 3;      // s-chunk 0..3

  // ---- Phase A: LayerNorm (lane = feature d), 8 rows per wave ----
  const float g  = gamma[lane];
  const float be = beta[lane];
  #pragma unroll
  for (int u = 0; u < 8; ++u) {
    int s_loc = w * 8 + u;
    int s     = sq * 32 + s_loc;
    float x = M[(s * I_ + i) * D_ + lane];
    float s1 = x, s2 = x * x;
    #pragma unroll
    for (int m = 1; m < 64; m <<= 1) {
      s1 += __shfl_xor(s1, m, 64);
      s2 += __shfl_xor(s2, m, 64);
    }
    float mean = s1 * (1.0f / 64.0f);
    float var  = s2 * (1.0f / 64.0f) - mean * mean;
    float xn   = (x - mean) * rsqrtf(var + 1e-5f) * g + be;
    mnAll[s_loc * 68 + lane] = xn;
  }
  __syncthreads();

  // ---- Phase B: projections (lane 0..31 = p via Wa, 32..63 = q via Wb) ----
  {
    const int p    = lane & 31;
    const int side = lane >> 5;
    const float* wrow = (side ? Wb : Wa) + p * D_;
    const float  bias = side ? bb[p] : ba[p];
    f32x4 wv[16];
    #pragma unroll
    for (int c = 0; c < 16; ++c) wv[c] = *(const f32x4*)(wrow + c * 4);
    float* dst = side ? rsm : lsm;
    #pragma unroll
    for (int u = 0; u < 8; ++u) {
      int s_loc = w * 8 + u;
      float acc = bias;
      #pragma unroll
      for (int c = 0; c < 16; ++c) {
        f32x4 m4 = *(const f32x4*)(&mnAll[s_loc * 68 + c * 4]);
        acc += m4.x * wv[c].x + m4.y * wv[c].y + m4.z * wv[c].z + m4.w * wv[c].w;
      }
      dst[s_loc * 33 + p] = acc;
    }
  }
  __syncthreads();

  // ---- Phase C: transpose write-out (bf16, u16x8) ----
  // 256 items: arr(2) x p(32) x c(4); each item = 8 consecutive s.
  {
    int arr = tid >> 7;
    int p   = (tid >> 2) & 31;
    int c   = tid & 3;
    int s0  = c * 8;
    const float* src = arr ? rsm : lsm;
    unsigned short* dstg = (arr ? RtT : LtT) + (i * 32 + p) * S_ + sq * 32 + s0;
    u16x8 v;
    #pragma unroll
    for (int k = 0; k < 8; ++k) v[k] = f2bf(src[(s0 + k) * 33 + p]);
    *(u16x8*)dstg = v;
  }
}

// ---------------------------------------------------------------------------
// K2: Wo -> WoP[o][k'] , k' = q*32 + p holds Wo[o][p*32+q]   (128 x 1024)
// ---------------------------------------------------------------------------
__global__ __launch_bounds__(256) void wo_pack(
    const float* __restrict__ Wo, unsigned short* __restrict__ WoP)
{
  int f  = blockIdx.x * 256 + threadIdx.x;
  int o  = f >> 10;
  int kp = f & 1023;
  int q  = kp >> 5;
  int p  = kp & 31;
  WoP[f] = f2bf(Wo[o * 1024 + p * 32 + q]);
}

// ---------------------------------------------------------------------------
// K3: fused GEMM. Block = 512 thr (8 waves), tile = 32 pairs (4i x 8j).
// Osh 32 x 1048 ushorts (67 KB) -> 2 blocks/CU.
// Column swizzle: k'=q*32+p stored at q*32+((p+8q)&31)  (same on read).
// ---------------------------------------------------------------------------
__global__ __launch_bounds__(512, 4) void fused_gemm(
    const unsigned short* __restrict__ LtT,
    const unsigned short* __restrict__ RtT,
    const unsigned short* __restrict__ WoP,
    const float* __restrict__ bo,
    float* __restrict__ Z)
{
  __shared__ __align__(16) unsigned short Osh[32 * 1048];   // 67072 B

  const int tid  = threadIdx.x;
  const int lane = tid & 63;
  const int wid  = tid >> 6;
  const int l15  = lane & 15;
  const int l4   = lane >> 4;

  // XCD-aware swizzle (2048 % 8 == 0 -> bijective)
  const int bid  = (int)(blockIdx.x & 7) * 256 + ((int)blockIdx.x >> 3);
  const int ti4  = bid >> 5;   // 0..63  (4 i-residues each)
  const int tj   = bid & 31;   // 0..31  (8 j-residues each)

  // ---------------- GEMM1: O[128 ip][256 jq], K = 128 ----------------
  {
    const int wr = wid >> 2;   // 0..1 : ip half [wr*64, +64)
    const int wc = wid & 3;    // 0..3 : jq quarter [wc*64, +64)
    f32x4 acc[4][4];
    #pragma unroll
    for (int a = 0; a < 4; ++a)
      #pragma unroll
      for (int b = 0; b < 4; ++b) { f32x4 z = {0.f, 0.f, 0.f, 0.f}; acc[a][b] = z; }

    #pragma unroll
    for (int kk = 0; kk < 4; ++kk) {
      bf16x8 af[4], bfr[4];
      #pragma unroll
      for (int rt = 0; rt < 4; ++rt) {
        int row = ti4 * 128 + wr * 64 + rt * 16 + l15;    // LtT row
        af[rt] = *(const bf16x8*)(LtT + row * S_ + kk * 32 + l4 * 8);
      }
      #pragma unroll
      for (int ct = 0; ct < 4; ++ct) {
        int row = tj * 256 + wc * 64 + ct * 16 + l15;     // RtT row
        bfr[ct] = *(const bf16x8*)(RtT + row * S_ + kk * 32 + l4 * 8);
      }
      #pragma unroll
      for (int rt = 0; rt < 4; ++rt)
        #pragma unroll
        for (int ct = 0; ct < 4; ++ct)
          acc[rt][ct] = __builtin_amdgcn_mfma_f32_16x16x32_bf16(
              af[rt], bfr[ct], acc[rt][ct], 0, 0, 0);
    }

    // O -> LDS (bf16, swizzled). D-layout: col=l15 (jq), row=l4*4+r (ip).
    #pragma unroll
    for (int rt = 0; rt < 4; ++rt) {
      int ip_loc = wr * 64 + rt * 16 + l4 * 4;            // + r
      int li = ip_loc >> 5;
      int p0 = ip_loc & 31;                               // multiple of 4
      #pragma unroll
      for (int ct = 0; ct < 4; ++ct) {
        int jq_loc = wc * 64 + ct * 16 + l15;
        int lj = jq_loc >> 5, q = jq_loc & 31;
        int col = q * 32 + ((p0 + 8 * q) & 31);           // swizzled, mult of 4
        u16x4 v;
        v.x = f2bf(acc[rt][ct][0]);
        v.y = f2bf(acc[rt][ct][1]);
        v.z = f2bf(acc[rt][ct][2]);
        v.w = f2bf(acc[rt][ct][3]);
        *(u16x4*)(Osh + (li * 8 + lj) * 1048 + col) = v;
      }
    }
  }
  __syncthreads();

  // ---------------- GEMM2: Z[32 pairs][128 o] = Osh * WoP^T + bo ----------------
  {
    const int wm = wid >> 2;   // 0..1 : pair rows [wm*16, +16)
    const int wn = wid & 3;    // 0..3 : o cols [wn*32, +32)
    f32x4 zacc[2];
    #pragma unroll
    for (int b = 0; b < 2; ++b) { f32x4 z = {0.f, 0.f, 0.f, 0.f}; zacc[b] = z; }

    const unsigned short* wop_base = WoP + (wn * 32 + l15) * 1024 + l4 * 8;
    const unsigned short* osh_base = Osh + (wm * 16 + l15) * 1048;

    #pragma unroll 2
    for (int kk2 = 0; kk2 < 32; ++kk2) {
      bf16x8 wfr[2];
      #pragma unroll
      for (int ctb = 0; ctb < 2; ++ctb)
        wfr[ctb] = *(const bf16x8*)(wop_base + ctb * 16 * 1024 + kk2 * 32);
      bf16x8 afr = *(const bf16x8*)(osh_base + kk2 * 32 + ((l4 * 8 + 8 * kk2) & 31));
      #pragma unroll
      for (int ctb = 0; ctb < 2; ++ctb)
        zacc[ctb] = __builtin_amdgcn_mfma_f32_16x16x32_bf16(
            afr, wfr[ctb], zacc[ctb], 0, 0, 0);
    }

    float bov[2];
    #pragma unroll
    for (int ctb = 0; ctb < 2; ++ctb) bov[ctb] = bo[wn * 32 + ctb * 16 + l15];

    #pragma unroll
    for (int r = 0; r < 4; ++r) {
      int pair = wm * 16 + l4 * 4 + r;
      int li = pair >> 3, lj = pair & 7;
      float* zrow = Z + ((ti4 * 4 + li) * I_ + (tj * 8 + lj)) * DO_;
      #pragma unroll
      for (int ctb = 0; ctb < 2; ++ctb)
        zrow[wn * 32 + ctb * 16 + l15] = zacc[ctb][r] + bov[ctb];
    }
  }
}

// ---------------------------------------------------------------------------
extern "C" void kernel_launch(void* const* d_in, const int* in_sizes, int n_in,
                              void* d_out, int out_size, void* d_ws, size_t ws_size,
                              hipStream_t stream) {
  const float* M     = (const float*)d_in[0];
  const float* gamma = (const float*)d_in[1];
  const float* beta  = (const float*)d_in[2];
  const float* Wa    = (const float*)d_in[3];
  const float* ba    = (const float*)d_in[4];
  const float* Wb    = (const float*)d_in[5];
  const float* bb    = (const float*)d_in[6];
  const float* Wo    = (const float*)d_in[7];
  const float* bo    = (const float*)d_in[8];
  float* Z = (float*)d_out;

  unsigned short* LtT = (unsigned short*)d_ws;
  unsigned short* RtT = LtT + 1048576;
  unsigned short* WoP = RtT + 1048576;

  ln_proj<<<1024, 256, 0, stream>>>(M, gamma, beta, Wa, ba, Wb, bb, LtT, RtT);
  wo_pack<<<512, 256, 0, stream>>>(Wo, WoP);
  fused_gemm<<<2048, 512, 0, stream>>>(LtT, RtT, WoP, bo, Z);
}

// Round 6
// 126.230 us; speedup vs baseline: 2.1433x; 2.1433x over previous
//
#include <hip/hip_runtime.h>

typedef __attribute__((ext_vector_type(4))) float          f32x4;
typedef __attribute__((ext_vector_type(8))) short          bf16x8;
typedef __attribute__((ext_vector_type(4))) unsigned short u16x4;
typedef __attribute__((ext_vector_type(8))) unsigned short u16x8;

__device__ __forceinline__ unsigned short f2bf(float f) {
  union { float f; unsigned u; } v; v.f = f;
  unsigned r = v.u + 0x7fffu + ((v.u >> 16) & 1u);   // RNE
  return (unsigned short)(r >> 16);
}

// async global -> LDS, 16 B per lane per inst (1 KB per wave-inst).
// LDS dest is wave-uniform base + lane*16 (pass uniform base).
__device__ __forceinline__ void gload_lds16(const void* g, void* l) {
  __builtin_amdgcn_global_load_lds(
      (const __attribute__((address_space(1))) unsigned int*)g,
      (__attribute__((address_space(3))) unsigned int*)l, 16, 0, 0);
}

#define S_  128
#define I_  256
#define D_  64
#define P_  32
#define DO_ 128

// ---------------------------------------------------------------------------
// K1: LayerNorm + projections (grid 1024 = i x 4 s-chunks) + folded Wo pack
// (blocks < 512). Outputs:
//   LtT[i*32+p][s], RtT[j*32+q][s] (8192 x 128 bf16, 256 B rows)
//   WoP[o][k'] with k' = q*32+p holding Wo[o][p*32+q] (128 x 1024 bf16)
// ---------------------------------------------------------------------------
__global__ __launch_bounds__(256) void ln_proj(
    const float* __restrict__ M,  const float* __restrict__ gamma,
    const float* __restrict__ beta,
    const float* __restrict__ Wa, const float* __restrict__ ba,
    const float* __restrict__ Wb, const float* __restrict__ bb,
    const float* __restrict__ Wo,
    unsigned short* __restrict__ LtT, unsigned short* __restrict__ RtT,
    unsigned short* __restrict__ WoP)
{
  __shared__ __align__(16) float mnAll[32 * 68];
  __shared__ __align__(16) float lsm[32 * 33];
  __shared__ __align__(16) float rsm[32 * 33];

  const int tid  = threadIdx.x;
  const int lane = tid & 63;
  const int w    = tid >> 6;
  const int i    = blockIdx.x >> 2;
  const int sq   = blockIdx.x & 3;

  // Phase A: LayerNorm
  const float g  = gamma[lane];
  const float be = beta[lane];
  #pragma unroll
  for (int u = 0; u < 8; ++u) {
    int s_loc = w * 8 + u;
    int s     = sq * 32 + s_loc;
    float x = M[(s * I_ + i) * D_ + lane];
    float s1 = x, s2 = x * x;
    #pragma unroll
    for (int m = 1; m < 64; m <<= 1) {
      s1 += __shfl_xor(s1, m, 64);
      s2 += __shfl_xor(s2, m, 64);
    }
    float mean = s1 * (1.0f / 64.0f);
    float var  = s2 * (1.0f / 64.0f) - mean * mean;
    mnAll[s_loc * 68 + lane] = (x - mean) * rsqrtf(var + 1e-5f) * g + be;
  }
  __syncthreads();

  // Phase B: projections
  {
    const int p    = lane & 31;
    const int side = lane >> 5;
    const float* wrow = (side ? Wb : Wa) + p * D_;
    const float  bias = side ? bb[p] : ba[p];
    f32x4 wv[16];
    #pragma unroll
    for (int c = 0; c < 16; ++c) wv[c] = *(const f32x4*)(wrow + c * 4);
    float* dst = side ? rsm : lsm;
    #pragma unroll
    for (int u = 0; u < 8; ++u) {
      int s_loc = w * 8 + u;
      float acc = bias;
      #pragma unroll
      for (int c = 0; c < 16; ++c) {
        f32x4 m4 = *(const f32x4*)(&mnAll[s_loc * 68 + c * 4]);
        acc += m4.x * wv[c].x + m4.y * wv[c].y + m4.z * wv[c].z + m4.w * wv[c].w;
      }
      dst[s_loc * 33 + p] = acc;
    }
  }
  __syncthreads();

  // Phase C: transpose write-out
  {
    int arr = tid >> 7;
    int p   = (tid >> 2) & 31;
    int c   = tid & 3;
    int s0  = c * 8;
    const float* src = arr ? rsm : lsm;
    unsigned short* dstg = (arr ? RtT : LtT) + (i * 32 + p) * S_ + sq * 32 + s0;
    u16x8 v;
    #pragma unroll
    for (int k = 0; k < 8; ++k) v[k] = f2bf(src[(s0 + k) * 33 + p]);
    *(u16x8*)dstg = v;
  }

  // folded Wo pack (one element per thread, blocks 0..511)
  if (blockIdx.x < 512) {
    int f = (int)blockIdx.x * 256 + tid;
    int o = f >> 10, kp = f & 1023, q = kp >> 5, p = kp & 31;
    WoP[f] = f2bf(Wo[o * 1024 + p * 32 + q]);
  }
}

// ---------------------------------------------------------------------------
// K2: persistent fused GEMM. 256 blocks (1/CU), 512 thr (8 waves).
// Block (bi, bjp): i-slab of 8 residues, two j-slabs of 16 (bj = bjp, bjp+8).
// Per j-slab: 8 k'-chunks of 128 (4 q): GEMM1 (LtS x RtS_c -> acc) ->
// Osh_c -> GEMM2 (Osh_c x WoPS_c -> zacc). All staged tiles are
// [rows][128 bf16] (256 B rows) with byte swizzle col ^= (row&7)<<4, folded
// into the global source address at staging time (linear LDS dest).
// LDS: LtS 64K | RtS 16K | WoPS 32K | Osh 32K = 144 KB.
// ---------------------------------------------------------------------------
__global__ __launch_bounds__(512, 2) void fused_gemm(
    const unsigned short* __restrict__ LtT,
    const unsigned short* __restrict__ RtT,
    const unsigned short* __restrict__ WoP,
    const float* __restrict__ bo,
    float* __restrict__ Z)
{
  __shared__ __align__(16) unsigned short ldsmem[73728];   // 147456 B
  char* Lc  = (char*)ldsmem;
  char* LtS = Lc;
  char* RtS = Lc + 65536;
  char* WoS = Lc + 81920;
  char* Osh = Lc + 114688;

  const int tid  = threadIdx.x;
  const int lane = tid & 63;
  const int wid  = tid >> 6;
  const int l15  = lane & 15;
  const int l4   = lane >> 4;

  const int bid = ((int)blockIdx.x & 7) * 32 + ((int)blockIdx.x >> 3); // XCD swz
  const int bi  = bid >> 3;    // 0..31 (8 i each)
  const int bjp = bid & 7;     // 0..7  (bj = bjp, bjp+8)

  // ---- prologue: stage LtS (64 KB, persistent) ----
  {
    const char* g = (const char*)LtT + (unsigned)bi * 65536u;
    #pragma unroll
    for (int t2 = 0; t2 < 8; ++t2) {
      int t = wid + t2 * 8;
      unsigned off = (unsigned)t * 1024u;
      unsigned y = off + (unsigned)lane * 16u;
      unsigned r = y >> 8, cb = y & 255u;
      gload_lds16(g + r * 256u + (cb ^ ((r & 7u) << 4)), LtS + off);
    }
  }

  const int wm = wid >> 2;   // GEMM2: pair-quadrant (4 Mtiles)
  const int wn = wid & 3;    // GEMM2: o-quadrant   (2 Ntiles)

  float bov[2];
  #pragma unroll
  for (int n_i = 0; n_i < 2; ++n_i) bov[n_i] = bo[(wn * 2 + n_i) * 16 + l15];

  f32x4 zacc[4][2];
  #pragma unroll
  for (int a = 0; a < 4; ++a)
    #pragma unroll
    for (int b = 0; b < 2; ++b) { f32x4 zz = {0.f,0.f,0.f,0.f}; zacc[a][b] = zz; }

  bf16x8 af[4][2];   // A-fragments (LtS), held in registers across all chunks

  for (int jj = 0; jj < 2; ++jj) {
    const int bj = bjp + jj * 8;

    // stage RtS chunk 0 + WoPS chunk 0 (drained at the barrier below)
    #pragma unroll
    for (int t2 = 0; t2 < 2; ++t2) {
      int t = wid + t2 * 8;
      unsigned off = (unsigned)t * 1024u;
      unsigned y = off + (unsigned)lane * 16u;
      unsigned lr = y >> 8, cb = y & 255u;
      unsigned grow = (unsigned)bj * 512u + (lr >> 2) * 32u + 0u * 4u + (lr & 3u);
      gload_lds16((const char*)RtT + grow * 256u + (cb ^ ((lr & 7u) << 4)), RtS + off);
    }
    #pragma unroll
    for (int t2 = 0; t2 < 4; ++t2) {
      int t = wid + t2 * 8;
      unsigned off = (unsigned)t * 1024u;
      unsigned y = off + (unsigned)lane * 16u;
      unsigned o = y >> 8, cb = y & 255u;
      gload_lds16((const char*)WoP + o * 2048u + 0u * 256u + (cb ^ ((o & 7u) << 4)), WoS + off);
    }

    if (jj == 1) {
      // write out Z for the previous j-slab (overlaps staging), re-zero zacc
      const int bjo = bjp;
      #pragma unroll
      for (int m_i = 0; m_i < 4; ++m_i)
        #pragma unroll
        for (int r = 0; r < 4; ++r) {
          int pair = (wm * 4 + m_i) * 16 + l4 * 4 + r;
          int i_loc = pair >> 4, j_loc = pair & 15;
          float* zrow = Z + (((bi * 8 + i_loc) * I_) + (bjo * 16 + j_loc)) * DO_;
          #pragma unroll
          for (int n_i = 0; n_i < 2; ++n_i)
            zrow[(wn * 2 + n_i) * 16 + l15] = zacc[m_i][n_i][r] + bov[n_i];
        }
      #pragma unroll
      for (int a = 0; a < 4; ++a)
        #pragma unroll
        for (int b = 0; b < 2; ++b) { f32x4 zz = {0.f,0.f,0.f,0.f}; zacc[a][b] = zz; }
    }

    __syncthreads();   // staged data visible (compiler drains vmcnt)

    if (jj == 0) {
      // hoist LtS A-fragments to registers (once)
      #pragma unroll
      for (int kk = 0; kk < 4; ++kk)
        #pragma unroll
        for (int ai = 0; ai < 2; ++ai) {
          unsigned r = (unsigned)((wid * 2 + ai) * 16 + l15);
          af[kk][ai] = *(const bf16x8*)(LtS + r * 256u +
                         (((unsigned)(kk * 64 + l4 * 16)) ^ ((r & 7u) << 4)));
        }
    }

    for (int c = 0; c < 8; ++c) {
      // ---------------- GEMM1_c ----------------
      f32x4 acc[2][4];
      #pragma unroll
      for (int a = 0; a < 2; ++a)
        #pragma unroll
        for (int b = 0; b < 4; ++b) { f32x4 zz = {0.f,0.f,0.f,0.f}; acc[a][b] = zz; }

      #pragma unroll
      for (int kk = 0; kk < 4; ++kk) {
        bf16x8 bfr[4];
        #pragma unroll
        for (int bt = 0; bt < 4; ++bt) {
          unsigned r = (unsigned)(bt * 16 + l15);
          bfr[bt] = *(const bf16x8*)(RtS + r * 256u +
                      (((unsigned)(kk * 64 + l4 * 16)) ^ ((r & 7u) << 4)));
        }
        #pragma unroll
        for (int ai = 0; ai < 2; ++ai)
          #pragma unroll
          for (int bt = 0; bt < 4; ++bt)
            acc[ai][bt] = __builtin_amdgcn_mfma_f32_16x16x32_bf16(
                af[kk][ai], bfr[bt], acc[ai][bt], 0, 0, 0);
      }

      // ---------------- O -> Osh (bf16, swizzled) ----------------
      #pragma unroll
      for (int ai = 0; ai < 2; ++ai) {
        int at = wid * 2 + ai;
        unsigned prhi = (unsigned)(at >> 1) * 16u;
        unsigned p0   = (unsigned)((at & 1) * 16 + l4 * 4);
        #pragma unroll
        for (int bt = 0; bt < 4; ++bt) {
          unsigned pair = prhi + (unsigned)(bt * 4) + ((unsigned)l15 >> 2);
          unsigned cb   = ((unsigned)l15 & 3u) * 64u + p0 * 2u;
          u16x4 v;
          v.x = f2bf(acc[ai][bt][0]);
          v.y = f2bf(acc[ai][bt][1]);
          v.z = f2bf(acc[ai][bt][2]);
          v.w = f2bf(acc[ai][bt][3]);
          *(u16x4*)(Osh + pair * 256u + (cb ^ ((pair & 7u) << 4))) = v;
        }
      }

      __syncthreads();   // B2: Osh visible; RtS_c consumed

      // stage RtS chunk c+1 (overlaps GEMM2, drains at B3)
      if (c < 7) {
        #pragma unroll
        for (int t2 = 0; t2 < 2; ++t2) {
          int t = wid + t2 * 8;
          unsigned off = (unsigned)t * 1024u;
          unsigned y = off + (unsigned)lane * 16u;
          unsigned lr = y >> 8, cb = y & 255u;
          unsigned grow = (unsigned)bj * 512u + (lr >> 2) * 32u +
                          (unsigned)(c + 1) * 4u + (lr & 3u);
          gload_lds16((const char*)RtT + grow * 256u + (cb ^ ((lr & 7u) << 4)),
                      RtS + off);
        }
      }

      // ---------------- GEMM2_c ----------------
      #pragma unroll
      for (int kk2 = 0; kk2 < 4; ++kk2) {
        bf16x8 afr[4], wbr[2];
        #pragma unroll
        for (int m_i = 0; m_i < 4; ++m_i) {
          unsigned r = (unsigned)((wm * 4 + m_i) * 16 + l15);
          afr[m_i] = *(const bf16x8*)(Osh + r * 256u +
                       (((unsigned)(kk2 * 64 + l4 * 16)) ^ ((r & 7u) << 4)));
        }
        #pragma unroll
        for (int n_i = 0; n_i < 2; ++n_i) {
          unsigned r = (unsigned)((wn * 2 + n_i) * 16 + l15);
          wbr[n_i] = *(const bf16x8*)(WoS + r * 256u +
                       (((unsigned)(kk2 * 64 + l4 * 16)) ^ ((r & 7u) << 4)));
        }
        #pragma unroll
        for (int m_i = 0; m_i < 4; ++m_i)
          #pragma unroll
          for (int n_i = 0; n_i < 2; ++n_i)
            zacc[m_i][n_i] = __builtin_amdgcn_mfma_f32_16x16x32_bf16(
                afr[m_i], wbr[n_i], zacc[m_i][n_i], 0, 0, 0);
      }

      __syncthreads();   // B3: WoPS_c consumed; RtS_{c+1} staged

      // stage WoPS chunk c+1 (overlaps next GEMM1, drains at next B2)
      if (c < 7) {
        #pragma unroll
        for (int t2 = 0; t2 < 4; ++t2) {
          int t = wid + t2 * 8;
          unsigned off = (unsigned)t * 1024u;
          unsigned y = off + (unsigned)lane * 16u;
          unsigned o = y >> 8, cb = y & 255u;
          gload_lds16((const char*)WoP + o * 2048u + (unsigned)(c + 1) * 256u +
                      (cb ^ ((o & 7u) << 4)), WoS + off);
        }
      }
    }
  }

  // final write-out (j-slab bjp+8)
  {
    const int bjo = bjp + 8;
    #pragma unroll
    for (int m_i = 0; m_i < 4; ++m_i)
      #pragma unroll
      for (int r = 0; r < 4; ++r) {
        int pair = (wm * 4 + m_i) * 16 + l4 * 4 + r;
        int i_loc = pair >> 4, j_loc = pair & 15;
        float* zrow = Z + (((bi * 8 + i_loc) * I_) + (bjo * 16 + j_loc)) * DO_;
        #pragma unroll
        for (int n_i = 0; n_i < 2; ++n_i)
          zrow[(wn * 2 + n_i) * 16 + l15] = zacc[m_i][n_i][r] + bov[n_i];
      }
  }
}

// ---------------------------------------------------------------------------
extern "C" void kernel_launch(void* const* d_in, const int* in_sizes, int n_in,
                              void* d_out, int out_size, void* d_ws, size_t ws_size,
                              hipStream_t stream) {
  const float* M     = (const float*)d_in[0];
  const float* gamma = (const float*)d_in[1];
  const float* beta  = (const float*)d_in[2];
  const float* Wa    = (const float*)d_in[3];
  const float* ba    = (const float*)d_in[4];
  const float* Wb    = (const float*)d_in[5];
  const float* bb    = (const float*)d_in[6];
  const float* Wo    = (const float*)d_in[7];
  const float* bo    = (const float*)d_in[8];
  float* Z = (float*)d_out;

  unsigned short* LtT = (unsigned short*)d_ws;
  unsigned short* RtT = LtT + 1048576;
  unsigned short* WoP = RtT + 1048576;

  ln_proj<<<1024, 256, 0, stream>>>(M, gamma, beta, Wa, ba, Wb, bb, Wo,
                                    LtT, RtT, WoP);
  fused_gemm<<<256, 512, 0, stream>>>(LtT, RtT, WoP, bo, Z);
}